// Round 3
// baseline (117.299 us; speedup 1.0000x reference)
//
#include <hip/hip_runtime.h>

// out[b,o,n] = sum_h W[n,o,h] * x[b,h,n] + bias[n,o]
// Per node: C[16b x 32o] = X[16b x 32h] . W_n[32o x 32h]^T  + bias
// -> one mfma_f32_16x16x32_bf16 per 16-wide o-half (K=32 in a single MFMA).

#define NT 16          // nodes per block (50000 % 16 == 0, no tail)
#define NN 50000
#define BATCH 16
#define CH 32
#define TPB 256        // 4 waves; each wave owns 4 nodes
#define BPAD 17        // padded b-dim -> 2-way (free) LDS bank aliasing

typedef __attribute__((ext_vector_type(8))) short bf16x8;
typedef __attribute__((ext_vector_type(4))) float f32x4;

__device__ inline short f2bf(float f) {
    // round-to-nearest-even f32 -> bf16 (inputs are finite, no NaN handling)
    union { float f; unsigned u; } v; v.f = f;
    unsigned r = (v.u + 0x7fffu + ((v.u >> 16) & 1u)) >> 16;
    return (short)r;
}

__global__ __launch_bounds__(TPB, 4)
void localconv1d_kernel(const float* __restrict__ x,
                        const float* __restrict__ W,
                        const float* __restrict__ bias,
                        float* __restrict__ out) {
    // x tile transposed: xs[nn][h][b], b padded to 17
    __shared__ float xs[NT * CH * BPAD];   // 34,816 B -> 4 blocks/CU

    const int tid  = threadIdx.x;
    const int lane = tid & 63;
    const int wv   = tid >> 6;            // wave 0..3
    const int n0   = blockIdx.x * NT;

    // ---- stage x: global [b][h][n] (coalesced float4 along n) -> xs[nn][h][b] ----
    {
        const int c4 = tid & 3;                    // which float4 along n
        #pragma unroll
        for (int p = 0; p < 8; ++p) {
            int row = p * 64 + (tid >> 2);         // 0..511 = b*CH + h
            int b   = row >> 5;
            int h   = row & 31;
            float4 v = *reinterpret_cast<const float4*>(
                x + (size_t)row * NN + n0 + c4 * 4);
            int nnb = c4 * 4;
            xs[((nnb + 0) * CH + h) * BPAD + b] = v.x;
            xs[((nnb + 1) * CH + h) * BPAD + b] = v.y;
            xs[((nnb + 2) * CH + h) * BPAD + b] = v.z;
            xs[((nnb + 3) * CH + h) * BPAD + b] = v.w;
        }
    }
    __syncthreads();

    const int bl = lane & 15;     // B-frag col = batch index, C col
    const int hc = lane >> 4;     // k-chunk (8 h each)

    f32x4 acc[4][2];              // [node-in-wave g][o-half H]

    #pragma unroll
    for (int g = 0; g < 4; ++g) {
        const int nn = wv * 4 + g;
        const int n  = n0 + nn;

        // B fragment (x): lane holds x[b=bl, h=hc*8+j, n], j=0..7
        float xv[8];
        #pragma unroll
        for (int j = 0; j < 8; ++j)
            xv[j] = xs[(nn * CH + hc * 8 + j) * BPAD + bl];
        bf16x8 bfrag;
        #pragma unroll
        for (int j = 0; j < 8; ++j) bfrag[j] = f2bf(xv[j]);

        #pragma unroll
        for (int H = 0; H < 2; ++H) {
            // A fragment (W): lane holds W[n, o=16H+bl, h=hc*8+j], contiguous in h
            const float* wp = W + (((size_t)n * CH) + 16 * H + bl) * CH + hc * 8;
            float4 w0 = *reinterpret_cast<const float4*>(wp);
            float4 w1 = *reinterpret_cast<const float4*>(wp + 4);
            bf16x8 afrag;
            afrag[0] = f2bf(w0.x); afrag[1] = f2bf(w0.y);
            afrag[2] = f2bf(w0.z); afrag[3] = f2bf(w0.w);
            afrag[4] = f2bf(w1.x); afrag[5] = f2bf(w1.y);
            afrag[6] = f2bf(w1.z); afrag[7] = f2bf(w1.w);

            // C init with bias: lane r-th acc = bias[n, 16H + 4*hc + r]
            f32x4 c = *reinterpret_cast<const f32x4*>(
                bias + (size_t)n * CH + 16 * H + 4 * hc);

            acc[g][H] = __builtin_amdgcn_mfma_f32_16x16x32_bf16(afrag, bfrag, c, 0, 0, 0);
        }
    }

    // ---- stores: lane holds C[o=16H+4hc+r][b=bl] for its wave's 4 nodes ----
    // float4 along n (g=0..3): out[(bl*CH + o)*NN + n0 + wv*4 + g]
    #pragma unroll
    for (int H = 0; H < 2; ++H) {
        #pragma unroll
        for (int r = 0; r < 4; ++r) {
            float4 vout;
            vout.x = acc[0][H][r];
            vout.y = acc[1][H][r];
            vout.z = acc[2][H][r];
            vout.w = acc[3][H][r];
            int o = 16 * H + 4 * hc + r;
            *reinterpret_cast<float4*>(
                out + ((size_t)bl * CH + o) * NN + n0 + wv * 4) = vout;
        }
    }
}

extern "C" void kernel_launch(void* const* d_in, const int* in_sizes, int n_in,
                              void* d_out, int out_size, void* d_ws, size_t ws_size,
                              hipStream_t stream) {
    const float* x    = (const float*)d_in[0];
    const float* W    = (const float*)d_in[1];
    const float* bias = (const float*)d_in[2];
    float* out        = (float*)d_out;

    localconv1d_kernel<<<NN / NT, TPB, 0, stream>>>(x, W, bias, out);
}

// Round 4
// 105.632 us; speedup vs baseline: 1.1104x; 1.1104x over previous
//
#include <hip/hip_runtime.h>

// out[b,o,n] = sum_h W[n,o,h] * x[b,h,n] + bias[n,o]
// x: [16][32][50000] f32, W: [50000][32][32] f32, bias: [50000][32] f32

#define NT 16          // nodes per block (50000 = 16 * 3125, no tail)
#define NN 50000
#define BATCH 16
#define CH 32
#define TPB 256
#define HP 36          // h-dim padded 32 -> 36 (16B-aligned rows, bank-friendly)
#define NXCD 8

__global__ __launch_bounds__(TPB, 4)
void localconv1d_kernel(const float* __restrict__ x,
                        const float* __restrict__ W,
                        const float* __restrict__ bias,
                        float* __restrict__ out) {
    // transposed x tile: xs[b][nn][h], h padded to 36 floats
    __shared__ float xs[BATCH * NT * HP];   // 36,864 B -> 4 blocks/CU

    const int tid = threadIdx.x;

    // ---- bijective XCD-aware block swizzle (nwg = 3125 = 8*390 + 5) ----
    const int nwg  = NN / NT;               // 3125
    const int q    = nwg / NXCD;            // 390
    const int r    = nwg % NXCD;            // 5
    const int orig = blockIdx.x;
    const int xcd  = orig % NXCD;
    const int wgid = (xcd < r ? xcd * (q + 1) : r * (q + 1) + (xcd - r) * q)
                     + orig / NXCD;
    const int n0 = wgid * NT;

    const int nn = tid & (NT - 1);
    const int og = tid >> 4;                // 0..15
    const int n  = n0 + nn;

    // ---- (1) issue x staging loads: 8 float4/thread, coalesced along n ----
    float4 xv[8];
    {
        const int c4 = tid & 3;             // float4 index within 16-node row
        #pragma unroll
        for (int p = 0; p < 8; ++p) {
            int row = p * 64 + (tid >> 2);  // 0..511 = b*CH + h
            xv[p] = *reinterpret_cast<const float4*>(
                x + (size_t)row * NN + n0 + c4 * 4);
        }
    }

    // ---- (2) issue all W loads (16 float4) + bias, then PIN in registers ----
    float4 w0[8], w1[8];
    const float4* W0 = reinterpret_cast<const float4*>(W + ((size_t)n * CH + og) * CH);
    const float4* W1 = reinterpret_cast<const float4*>(W + ((size_t)n * CH + og + 16) * CH);
    #pragma unroll
    for (int k = 0; k < 8; ++k) w0[k] = W0[k];
    #pragma unroll
    for (int k = 0; k < 8; ++k) w1[k] = W1[k];
    const float b0 = bias[(size_t)n * CH + og];
    const float b1 = bias[(size_t)n * CH + og + 16];
    #pragma unroll
    for (int k = 0; k < 8; ++k) {
        asm volatile("" :: "v"(w0[k].x), "v"(w0[k].y), "v"(w0[k].z), "v"(w0[k].w));
        asm volatile("" :: "v"(w1[k].x), "v"(w1[k].y), "v"(w1[k].z), "v"(w1[k].w));
    }

    // ---- (3) scatter x tile into transposed LDS layout xs[b][nn][h] ----
    {
        const int c4 = tid & 3;
        #pragma unroll
        for (int p = 0; p < 8; ++p) {
            int row = p * 64 + (tid >> 2);
            int b   = row >> 5;
            int h   = row & 31;
            int nb  = c4 * 4;
            xs[(b * NT + nb + 0) * HP + h] = xv[p].x;
            xs[(b * NT + nb + 1) * HP + h] = xv[p].y;
            xs[(b * NT + nb + 2) * HP + h] = xv[p].z;
            xs[(b * NT + nb + 3) * HP + h] = xv[p].w;
        }
    }
    __syncthreads();
    __builtin_amdgcn_sched_barrier(0);   // keep W loads/pins above the compute

    // ---- (4) compute: ds_read_b128 over h, two o-channels, 16 batches ----
    #pragma unroll
    for (int b = 0; b < BATCH; ++b) {
        float a0 = b0, a1 = b1;
        const float* xb = &xs[(b * NT + nn) * HP];
        #pragma unroll
        for (int k = 0; k < 8; ++k) {
            float4 xq = *reinterpret_cast<const float4*>(xb + k * 4);
            const float* w0p = reinterpret_cast<const float*>(&w0[k]);
            const float* w1p = reinterpret_cast<const float*>(&w1[k]);
            a0 = fmaf(w0p[0], xq.x, a0);  a1 = fmaf(w1p[0], xq.x, a1);
            a0 = fmaf(w0p[1], xq.y, a0);  a1 = fmaf(w1p[1], xq.y, a1);
            a0 = fmaf(w0p[2], xq.z, a0);  a1 = fmaf(w1p[2], xq.z, a1);
            a0 = fmaf(w0p[3], xq.w, a0);  a1 = fmaf(w1p[3], xq.w, a1);
        }
        out[((size_t)b * CH + og) * NN + n]      = a0;
        out[((size_t)b * CH + og + 16) * NN + n] = a1;
    }
}

extern "C" void kernel_launch(void* const* d_in, const int* in_sizes, int n_in,
                              void* d_out, int out_size, void* d_ws, size_t ws_size,
                              hipStream_t stream) {
    const float* x    = (const float*)d_in[0];
    const float* W    = (const float*)d_in[1];
    const float* bias = (const float*)d_in[2];
    float* out        = (float*)d_out;

    localconv1d_kernel<<<NN / NT, TPB, 0, stream>>>(x, W, bias, out);
}